// Round 5
// baseline (244.019 us; speedup 1.0000x reference)
//
#include <hip/hip_runtime.h>
#include <hip/hip_bf16.h>

typedef unsigned short u16;
typedef __bf16 bf16x8 __attribute__((ext_vector_type(8)));
typedef float f32x4 __attribute__((ext_vector_type(4)));
typedef u16 u16x8 __attribute__((ext_vector_type(8)));

#define S_LEN 2048
#define DMODEL 512
#define NHEAD 8
#define DHEAD 64
#define KSPLIT 4
#define KRANGE (S_LEN / KSPLIT)  // 512 k-positions per block

static __device__ __forceinline__ float bf2f(u16 v) {
    union { unsigned u; float f; } cv; cv.u = ((unsigned)v) << 16; return cv.f;
}
static __device__ __forceinline__ u16 f2bf(float f) {
    union { float f; unsigned u; } cv; cv.f = f;
    unsigned u = cv.u;
    return (u16)((u + 0x7fffu + ((u >> 16) & 1u)) >> 16);  // RNE
}
static __device__ __forceinline__ bf16x8 ld8(const u16* p) {
    return *(const bf16x8*)p;
}
static __device__ __forceinline__ float rmax16(float v) {
    v = fmaxf(v, __shfl_xor(v, 1));
    v = fmaxf(v, __shfl_xor(v, 2));
    v = fmaxf(v, __shfl_xor(v, 4));
    v = fmaxf(v, __shfl_xor(v, 8));
    return v;
}
static __device__ __forceinline__ float rsum16(float v) {
    v += __shfl_xor(v, 1);
    v += __shfl_xor(v, 2);
    v += __shfl_xor(v, 4);
    v += __shfl_xor(v, 8);
    return v;
}
// XOR-swizzled LDS index for a [rows][64 u16] tile (16B blocks permuted by row).
static __device__ __forceinline__ int swz(int row, int col) {
    return row * 64 + ((((col >> 3) ^ (row & 7)) << 3) | (col & 7));
}

// ---------------- fused prep: qkv fp32->bf16 cvt | weight transpose->bf16 | mask flags ----
// grid.x partition: [0,3072) cvt, [3072,4096) transpose_w, [4096,6144) mask flags. 256 thr.
__global__ __launch_bounds__(256) void prep_kernel(
    const float* __restrict__ q, const float* __restrict__ k, const float* __restrict__ v,
    const float* __restrict__ w0, const float* __restrict__ w1,
    const float* __restrict__ w2, const float* __restrict__ w3,
    const float* __restrict__ mask,
    u16* __restrict__ Aqkv, u16* __restrict__ wtall, int* __restrict__ flags) {
    const int p = blockIdx.x;
    const int tid = threadIdx.x;
    __shared__ float t[32][33];
    __shared__ int wred[4];
    if (p < 3072) {
        // fp32 -> bf16, 8 elems/thread
        const int z = p >> 10, px = p & 1023;
        const float* in = (z == 0) ? q : (z == 1) ? k : v;
        u16* o = Aqkv + (long)z * 2097152;
        long i = ((long)px * 256 + tid) * 8;
        f32x4 a = *(const f32x4*)(in + i);
        f32x4 b = *(const f32x4*)(in + i + 4);
        u16x8 r;
#pragma unroll
        for (int j = 0; j < 4; ++j) { r[j] = f2bf(a[j]); r[4 + j] = f2bf(b[j]); }
        *(u16x8*)(o + i) = r;
    } else if (p < 4096) {
        // W (512x512 fp32) -> Wt bf16 (N x K). slot order in wtall: [wo, wq, wk, wv]
        const int p2 = p - 3072;
        const int z = p2 >> 8, rem = p2 & 255, by = rem >> 4, bx = rem & 15;
        const float* in = (z == 0) ? w0 : (z == 1) ? w1 : (z == 2) ? w2 : w3;
        u16* o = wtall + (long)(((z + 1) & 3)) * 262144;
        const int tx = tid & 31, ty = tid >> 5;
#pragma unroll
        for (int i = 0; i < 4; ++i)
            t[ty + 8 * i][tx] = in[(by * 32 + ty + 8 * i) * DMODEL + bx * 32 + tx];
        __syncthreads();
#pragma unroll
        for (int i = 0; i < 4; ++i)
            o[(bx * 32 + ty + 8 * i) * DMODEL + by * 32 + tx] = f2bf(t[tx][ty + 8 * i]);
    } else {
        // per 64x64 mask tile nonzero flag
        const int bid = p - 4096;  // 2*32*32
        const int b = bid >> 10, qt = (bid >> 5) & 31, kt = bid & 31;
        const int r = tid >> 2, cs = tid & 3;
        const float* mp = mask + ((long)(b * S_LEN + qt * 64 + r)) * S_LEN + kt * 64 + cs * 16;
        int nz = 0;
#pragma unroll
        for (int j = 0; j < 4; ++j) {
            f32x4 a = *(const f32x4*)(mp + j * 4);
            nz |= (a[0] != 0.f) | (a[1] != 0.f) | (a[2] != 0.f) | (a[3] != 0.f);
        }
        unsigned long long ball = __ballot(nz);
        if ((tid & 63) == 0) wred[tid >> 6] = (ball != 0ull) ? 1 : 0;
        __syncthreads();
        if (tid == 0) flags[bid] = wred[0] | wred[1] | wred[2] | wred[3];
    }
}

// V merged bf16 (B,S,512) -> Vt bf16 (B,H,DH,S)
__global__ void transpose_v_kernel(const u16* __restrict__ V, u16* __restrict__ Vt) {
    int z = blockIdx.z;
    int b = z >> 3, h = z & 7;
    const u16* in = V + (long)b * S_LEN * DMODEL + h * DHEAD;
    u16* out = Vt + (long)z * DHEAD * S_LEN;
    __shared__ u16 t[32][33];
    int tx = threadIdx.x, ty = threadIdx.y;
    int r = blockIdx.y * 32 + ty;  // s
    int c = blockIdx.x * 32 + tx;  // d
    t[ty][tx] = in[(long)r * DMODEL + c];
    __syncthreads();
    int orow = blockIdx.x * 32 + ty;  // d
    int ocol = blockIdx.y * 32 + tx;  // s
    out[(long)orow * S_LEN + ocol] = t[tx][ty];
}

// ---------------- GEMM: C(4096x512) = A(4096x512) @ W + bias; 64x64 block tile, 4 waves of 32x32
template <bool F32OUT>
static __device__ __forceinline__ void gemm_body64(const u16* __restrict__ A,
                                                   const u16* __restrict__ Wt,
                                                   const float* __restrict__ bias,
                                                   void* __restrict__ Cp, float oscale) {
    const int lane = threadIdx.x & 63;
    const int wave = threadIdx.x >> 6;
    const int wr = wave >> 1, wc = wave & 1;
    const int m0 = blockIdx.y * 64 + wr * 32;
    const int n0 = blockIdx.x * 64 + wc * 32;
    const int cidx = lane & 15;
    const int kg = lane >> 4;

    const u16* aptr[2];
    const u16* bptr[2];
#pragma unroll
    for (int t = 0; t < 2; ++t) {
        aptr[t] = A + (long)(m0 + t * 16 + cidx) * DMODEL + kg * 8;
        bptr[t] = Wt + (long)(n0 + t * 16 + cidx) * DMODEL + kg * 8;
    }
    const f32x4 fz = {0.f, 0.f, 0.f, 0.f};
    f32x4 acc[2][2];
#pragma unroll
    for (int i = 0; i < 2; ++i)
#pragma unroll
        for (int j = 0; j < 2; ++j) acc[i][j] = fz;

#pragma unroll 4
    for (int k0 = 0; k0 < 512; k0 += 32) {
        bf16x8 a[2], b[2];
#pragma unroll
        for (int t = 0; t < 2; ++t) a[t] = ld8(aptr[t] + k0);
#pragma unroll
        for (int t = 0; t < 2; ++t) b[t] = ld8(bptr[t] + k0);
#pragma unroll
        for (int i = 0; i < 2; ++i)
#pragma unroll
            for (int j = 0; j < 2; ++j)
                acc[i][j] = __builtin_amdgcn_mfma_f32_16x16x32_bf16(a[i], b[j], acc[i][j], 0, 0, 0);
    }

#pragma unroll
    for (int j = 0; j < 2; ++j) {
        int col = n0 + j * 16 + cidx;
        float bv = bias[col];
#pragma unroll
        for (int i = 0; i < 2; ++i) {
#pragma unroll
            for (int r = 0; r < 4; ++r) {
                int row = m0 + i * 16 + kg * 4 + r;
                float val = (acc[i][j][r] + bv) * oscale;
                if (F32OUT) {
                    ((float*)Cp)[(long)row * DMODEL + col] = val;
                } else {
                    ((u16*)Cp)[(long)row * DMODEL + col] = f2bf(val);
                }
            }
        }
    }
}

__global__ __launch_bounds__(256) void qkv_gemm_kernel(
    const u16* __restrict__ Aqkv,
    const u16* __restrict__ wtall,
    const float* __restrict__ bq, const float* __restrict__ bk, const float* __restrict__ bv,
    u16* __restrict__ Q, u16* __restrict__ K, u16* __restrict__ V) {
    const u16* A = Aqkv + (long)blockIdx.z * 2097152;
    const u16* W = wtall + (long)(blockIdx.z + 1) * 262144;  // [wo, wq, wk, wv]
    const float* b;
    u16* C;
    float sc = 1.f;
    if (blockIdx.z == 0) { b = bq; C = Q; sc = 0.125f; }  // fold 1/sqrt(DH) into Q
    else if (blockIdx.z == 1) { b = bk; C = K; }
    else { b = bv; C = V; }
    gemm_body64<false>(A, W, b, C, sc);
}

__global__ __launch_bounds__(256) void out_gemm_kernel(const u16* __restrict__ A,
                                                       const u16* __restrict__ Wt,
                                                       const float* __restrict__ bias,
                                                       float* __restrict__ C) {
    gemm_body64<true>(A, Wt, bias, C, 1.f);
}

// ---------------- flash attention, K-split=4, swizzled LDS, mask fast-path ----------------
// grid: (S/64, B*H, KSPLIT), block 256 (4 waves). Wave w owns 16 q-rows.
__global__ __launch_bounds__(256) void attn_kernel(const u16* __restrict__ Q,
                                                   const u16* __restrict__ K,
                                                   const u16* __restrict__ Vt,
                                                   const float* __restrict__ mask,
                                                   const int* __restrict__ flags,
                                                   u16* __restrict__ Opart,
                                                   float* __restrict__ ML) {
    const int tid = threadIdx.x;
    const int lane = tid & 63;
    const int wave = tid >> 6;
    const int cidx = lane & 15;
    const int kg = lane >> 4;
    const int bh = blockIdx.y;
    const int b = bh >> 3, h = bh & 7;
    const int q0 = blockIdx.x * 64 + wave * 16;
    const int z = blockIdx.z;
    const int k0z = z * KRANGE;

    __shared__ u16 kt_lds[64 * 64];   // [key-local][dh], XOR-swizzled
    __shared__ u16 vt_lds[64 * 64];   // [dh][key-local], XOR-swizzled
    __shared__ u16 p_lds[4][16 * 64]; // per-wave P tile, XOR-swizzled
    u16* pw = p_lds[wave];

    // Q fragments (A-layout): row = q0 + cidx, k = kg*8 + j (+32 for 2nd half)
    const long qbase = ((long)(b * S_LEN + q0 + cidx)) * DMODEL + h * DHEAD + kg * 8;
    bf16x8 aq0 = ld8(Q + qbase);
    bf16x8 aq1 = ld8(Q + qbase + 32);

    const f32x4 fz = {0.f, 0.f, 0.f, 0.f};
    f32x4 acc[4];
#pragma unroll
    for (int nt = 0; nt < 4; ++nt) acc[nt] = fz;
    float mrow[4] = {-1e30f, -1e30f, -1e30f, -1e30f};
    float lrow[4] = {0.f, 0.f, 0.f, 0.f};

    // staging roles: 512 16B slots over 256 threads
    const int krow0 = tid >> 3, kseg0 = tid & 7;  // rows 0..31
    const int krow1 = krow0 + 32;                 // rows 32..63
    const u16* kgbase = K + ((long)(b * S_LEN + k0z)) * DMODEL + h * DHEAD;
    const u16* vgbase = Vt + ((long)bh * DHEAD) * S_LEN + k0z;
    const int kd0 = swz(krow0, kseg0 * 8);
    const int kd1 = swz(krow1, kseg0 * 8);
    const int* flagrow = flags + b * 1024 + blockIdx.x * 32 + z * (KRANGE / 64);

    for (int it = 0; it < KRANGE / 64; ++it) {
        const int kt = it * 64;
        const int flg = flagrow[it];
        __syncthreads();  // previous iteration's LDS reads complete
        // ---- cooperative staging (K tile + V tile) ----
        *(u16x8*)&kt_lds[kd0] = *(const u16x8*)(kgbase + (long)(kt + krow0) * DMODEL + kseg0 * 8);
        *(u16x8*)&kt_lds[kd1] = *(const u16x8*)(kgbase + (long)(kt + krow1) * DMODEL + kseg0 * 8);
        *(u16x8*)&vt_lds[kd0] = *(const u16x8*)(vgbase + (long)krow0 * S_LEN + kt + kseg0 * 8);
        *(u16x8*)&vt_lds[kd1] = *(const u16x8*)(vgbase + (long)krow1 * S_LEN + kt + kseg0 * 8);
        __syncthreads();

        // ---- S tile = Q K^T : 16 x 64 (Q pre-scaled by 1/8) ----
        f32x4 sacc[4];
#pragma unroll
        for (int ct = 0; ct < 4; ++ct) sacc[ct] = fz;
#pragma unroll
        for (int ct = 0; ct < 4; ++ct) {
            int r = ct * 16 + cidx;
            bf16x8 bk0 = ld8(&kt_lds[r * 64 + ((kg ^ (r & 7)) << 3)]);
            bf16x8 bk1 = ld8(&kt_lds[r * 64 + (((4 ^ kg) ^ (r & 7)) << 3)]);
            sacc[ct] = __builtin_amdgcn_mfma_f32_16x16x32_bf16(aq0, bk0, sacc[ct], 0, 0, 0);
            sacc[ct] = __builtin_amdgcn_mfma_f32_16x16x32_bf16(aq1, bk1, sacc[ct], 0, 0, 0);
        }
        // mask slow path (rare; fp32 direct from global, exact)
        if (flg) {
            const float* mb = mask + ((long)(b * S_LEN + q0 + kg * 4)) * S_LEN + k0z + kt + cidx;
#pragma unroll
            for (int ct = 0; ct < 4; ++ct)
#pragma unroll
                for (int r = 0; r < 4; ++r)
                    sacc[ct][r] -= 1e9f * mb[(long)r * S_LEN + ct * 16];
        }
        // ---- online softmax per owned row ----
        float pvv[4][4];
#pragma unroll
        for (int r = 0; r < 4; ++r) {
            float mx = fmaxf(fmaxf(sacc[0][r], sacc[1][r]), fmaxf(sacc[2][r], sacc[3][r]));
            mx = rmax16(mx);
            float mnew = fmaxf(mrow[r], mx);
            float alpha = __expf(mrow[r] - mnew);
            mrow[r] = mnew;
            float s = 0.f;
#pragma unroll
            for (int ct = 0; ct < 4; ++ct) {
                float p = __expf(sacc[ct][r] - mnew);
                pvv[ct][r] = p;
                s += p;
            }
            s = rsum16(s);
            lrow[r] = lrow[r] * alpha + s;
#pragma unroll
            for (int nt = 0; nt < 4; ++nt) acc[nt][r] = acc[nt][r] * alpha;
        }
        // ---- P: C-layout -> per-wave LDS (swizzled) -> A-layout ----
#pragma unroll
        for (int ct = 0; ct < 4; ++ct) {
#pragma unroll
            for (int r = 0; r < 4; r += 2) {
                union { __hip_bfloat162 h; unsigned u; } cv;
                float2 f2; f2.x = pvv[ct][r]; f2.y = pvv[ct][r + 1];
                cv.h = __float22bfloat162_rn(f2);
                pw[swz(kg * 4 + r, ct * 16 + cidx)] = (u16)(cv.u & 0xffffu);
                pw[swz(kg * 4 + r + 1, ct * 16 + cidx)] = (u16)(cv.u >> 16);
            }
        }
        bf16x8 pf0 = ld8(&pw[cidx * 64 + ((kg ^ (cidx & 7)) << 3)]);
        bf16x8 pf1 = ld8(&pw[cidx * 64 + (((4 ^ kg) ^ (cidx & 7)) << 3)]);
        // ---- O += P V ----
#pragma unroll
        for (int nt = 0; nt < 4; ++nt) {
            int r = nt * 16 + cidx;
            bf16x8 v0 = ld8(&vt_lds[r * 64 + ((kg ^ (r & 7)) << 3)]);
            bf16x8 v1 = ld8(&vt_lds[r * 64 + (((4 ^ kg) ^ (r & 7)) << 3)]);
            acc[nt] = __builtin_amdgcn_mfma_f32_16x16x32_bf16(pf0, v0, acc[nt], 0, 0, 0);
            acc[nt] = __builtin_amdgcn_mfma_f32_16x16x32_bf16(pf1, v1, acc[nt], 0, 0, 0);
        }
    }
    // epilogue: write unnormalized partials + (m,l)
#pragma unroll
    for (int nt = 0; nt < 4; ++nt) {
#pragma unroll
        for (int r = 0; r < 4; ++r) {
            int row = q0 + kg * 4 + r;
            Opart[(((long)(z * 16 + bh)) * S_LEN + row) * DHEAD + nt * 16 + cidx] = f2bf(acc[nt][r]);
        }
    }
    if (cidx == 0) {
#pragma unroll
        for (int r = 0; r < 4; ++r) {
            int row = q0 + kg * 4 + r;
            long mi = ((long)(z * 16 + bh)) * S_LEN + row;
            ML[mi * 2] = mrow[r];
            ML[mi * 2 + 1] = lrow[r];
        }
    }
}

// combine KSPLIT partials -> merged bf16 (B,S,512). 8 cols/thread, 32 rows/block, grid 1024.
__global__ __launch_bounds__(256) void attn_combine_kernel(const u16* __restrict__ Opart,
                                                           const float* __restrict__ ML,
                                                           u16* __restrict__ Ab) {
    const int tid = threadIdx.x;
    const long rr = (long)blockIdx.x * 32 + (tid >> 3);  // bh*2048 + q
    const int c8 = (tid & 7) * 8;
    const int bh = (int)(rr >> 11);
    const int q = (int)(rr & 2047);
    const int b = bh >> 3, h = bh & 7;

    float m[KSPLIT], l[KSPLIT];
#pragma unroll
    for (int zz = 0; zz < KSPLIT; ++zz) {
        long mi = ((long)(zz * 16 + bh)) * S_LEN + q;
        m[zz] = ML[mi * 2];
        l[zz] = ML[mi * 2 + 1];
    }
    float M = m[0];
#pragma unroll
    for (int zz = 1; zz < KSPLIT; ++zz) M = fmaxf(M, m[zz]);
    float L = 0.f, e[KSPLIT];
#pragma unroll
    for (int zz = 0; zz < KSPLIT; ++zz) { e[zz] = __expf(m[zz] - M); L += e[zz] * l[zz]; }
    float o[8] = {0, 0, 0, 0, 0, 0, 0, 0};
#pragma unroll
    for (int zz = 0; zz < KSPLIT; ++zz) {
        bf16x8 ov = ld8(Opart + (((long)(zz * 16 + bh)) * S_LEN + q) * DHEAD + c8);
#pragma unroll
        for (int j = 0; j < 8; ++j) o[j] += e[zz] * (float)ov[j];
    }
    float invL = 1.f / L;
    u16x8 w;
#pragma unroll
    for (int j = 0; j < 8; ++j) w[j] = f2bf(o[j] * invL);
    *(u16x8*)(Ab + ((long)(b * S_LEN + q)) * DMODEL + h * DHEAD + c8) = w;
}

extern "C" void kernel_launch(void* const* d_in, const int* in_sizes, int n_in,
                              void* d_out, int out_size, void* d_ws, size_t ws_size,
                              hipStream_t stream) {
    const float* q_in = (const float*)d_in[0];
    const float* k_in = (const float*)d_in[1];
    const float* v_in = (const float*)d_in[2];
    const float* mask = (const float*)d_in[3];
    const float* wq = (const float*)d_in[4];
    const float* bq = (const float*)d_in[5];
    const float* wk = (const float*)d_in[6];
    const float* bk = (const float*)d_in[7];
    const float* wv = (const float*)d_in[8];
    const float* bv = (const float*)d_in[9];
    const float* wo = (const float*)d_in[10];
    const float* bo = (const float*)d_in[11];

    // ws layout (u16 units). Regions ordered so attn can alias dead space:
    u16* ws = (u16*)d_ws;
    u16* Qb = ws;                       // 2.1M  projected Q (pre-scaled 1/8)
    u16* Kb = Qb + 2097152;             // 2.1M
    u16* Vt = Kb + 2097152;             // 2.1M  V transposed (B,H,DH,S)
    u16* wtall = Vt + 2097152;          // 4 x 262144: [wo, wq, wk, wv]
    u16* Sreg = wtall + 4 * 262144;     // 3 x 2.1M: Aq,Ak,Av  (dead after qkv_gemm)
    u16* Vb = Sreg + 3 * 2097152;       // 2.1M  merged V    (dead after transpose_v)
    u16* Ab = Vb + 2097152;             // 2.1M  attention output (merged heads)
    int* mflags = (int*)(Ab + 2097152); // 2048 ints
    // aliases:
    u16* Opart = Sreg;                  // KSPLIT*16*2048*64 = 8.39M u16, spans Sreg+Vb (8.4M) ok
    float* ML = (float*)(wtall + 262144);  // 262144 floats over [wq,wk] slots (dead after qkv)

    prep_kernel<<<6144, 256, 0, stream>>>(q_in, k_in, v_in, wq, wk, wv, wo, mask,
                                          Sreg, wtall, mflags);
    qkv_gemm_kernel<<<dim3(8, 64, 3), 256, 0, stream>>>(Sreg, wtall, bq, bk, bv, Qb, Kb, Vb);
    transpose_v_kernel<<<dim3(2, 64, 16), dim3(32, 32), 0, stream>>>(Vb, Vt);
    attn_kernel<<<dim3(32, 16, KSPLIT), 256, 0, stream>>>(Qb, Kb, Vt, mask, mflags, Opart, ML);
    attn_combine_kernel<<<1024, 256, 0, stream>>>(Opart, ML, Ab);
    out_gemm_kernel<<<dim3(8, 64), 256, 0, stream>>>(Ab, wtall, bo, (float*)d_out);
}

// Round 6
// 235.034 us; speedup vs baseline: 1.0382x; 1.0382x over previous
//
#include <hip/hip_runtime.h>
#include <hip/hip_bf16.h>

typedef unsigned short u16;
typedef unsigned int u32;
typedef __bf16 bf16x8 __attribute__((ext_vector_type(8)));
typedef float f32x4 __attribute__((ext_vector_type(4)));
typedef u16 u16x8 __attribute__((ext_vector_type(8)));
typedef u32 u32x2 __attribute__((ext_vector_type(2)));

#define S_LEN 2048
#define DMODEL 512
#define NHEAD 8
#define DHEAD 64
#define KSPLIT 4
#define KRANGE (S_LEN / KSPLIT)  // 512 k-positions per block
// log2(e); Q is pre-scaled by 0.125*LOG2E so softmax runs in exp2 domain.
#define QSCALE 0.1803368801111204f
#define MASKC 1.4426950409e9f

static __device__ __forceinline__ float bf2f(u16 v) {
    union { unsigned u; float f; } cv; cv.u = ((unsigned)v) << 16; return cv.f;
}
static __device__ __forceinline__ u16 f2bf(float f) {
    union { float f; unsigned u; } cv; cv.f = f;
    unsigned u = cv.u;
    return (u16)((u + 0x7fffu + ((u >> 16) & 1u)) >> 16);  // RNE
}
static __device__ __forceinline__ u32 pk2bf(float a, float b) {
    union { __hip_bfloat162 h; u32 u; } cv;
    float2 f2; f2.x = a; f2.y = b;
    cv.h = __float22bfloat162_rn(f2);
    return cv.u;
}
static __device__ __forceinline__ bf16x8 ld8(const u16* p) {
    return *(const bf16x8*)p;
}

// ---------------- fused prep: qkv fp32->bf16 cvt | weight transpose->bf16 | mask flags ----
// grid.x partition: [0,3072) cvt, [3072,4096) transpose_w, [4096,6144) mask flags. 256 thr.
__global__ __launch_bounds__(256) void prep_kernel(
    const float* __restrict__ q, const float* __restrict__ k, const float* __restrict__ v,
    const float* __restrict__ w0, const float* __restrict__ w1,
    const float* __restrict__ w2, const float* __restrict__ w3,
    const float* __restrict__ mask,
    u16* __restrict__ Aqkv, u16* __restrict__ wtall, int* __restrict__ flags) {
    const int p = blockIdx.x;
    const int tid = threadIdx.x;
    __shared__ float t[32][33];
    __shared__ int wred[4];
    if (p < 3072) {
        const int z = p >> 10, px = p & 1023;
        const float* in = (z == 0) ? q : (z == 1) ? k : v;
        u16* o = Aqkv + (long)z * 2097152;
        long i = ((long)px * 256 + tid) * 8;
        f32x4 a = *(const f32x4*)(in + i);
        f32x4 b = *(const f32x4*)(in + i + 4);
        u16x8 r;
#pragma unroll
        for (int j = 0; j < 4; ++j) { r[j] = f2bf(a[j]); r[4 + j] = f2bf(b[j]); }
        *(u16x8*)(o + i) = r;
    } else if (p < 4096) {
        // W (512x512 fp32) -> Wt bf16 (N x K). slot order in wtall: [wo, wq, wk, wv]
        const int p2 = p - 3072;
        const int z = p2 >> 8, rem = p2 & 255, by = rem >> 4, bx = rem & 15;
        const float* in = (z == 0) ? w0 : (z == 1) ? w1 : (z == 2) ? w2 : w3;
        u16* o = wtall + (long)(((z + 1) & 3)) * 262144;
        const int tx = tid & 31, ty = tid >> 5;
#pragma unroll
        for (int i = 0; i < 4; ++i)
            t[ty + 8 * i][tx] = in[(by * 32 + ty + 8 * i) * DMODEL + bx * 32 + tx];
        __syncthreads();
#pragma unroll
        for (int i = 0; i < 4; ++i)
            o[(bx * 32 + ty + 8 * i) * DMODEL + by * 32 + tx] = f2bf(t[tx][ty + 8 * i]);
    } else {
        const int bid = p - 4096;  // 2*32*32
        const int b = bid >> 10, qt = (bid >> 5) & 31, kt = bid & 31;
        const int r = tid >> 2, cs = tid & 3;
        const float* mp = mask + ((long)(b * S_LEN + qt * 64 + r)) * S_LEN + kt * 64 + cs * 16;
        int nz = 0;
#pragma unroll
        for (int j = 0; j < 4; ++j) {
            f32x4 a = *(const f32x4*)(mp + j * 4);
            nz |= (a[0] != 0.f) | (a[1] != 0.f) | (a[2] != 0.f) | (a[3] != 0.f);
        }
        unsigned long long ball = __ballot(nz);
        if ((tid & 63) == 0) wred[tid >> 6] = (ball != 0ull) ? 1 : 0;
        __syncthreads();
        if (tid == 0) flags[bid] = wred[0] | wred[1] | wred[2] | wred[3];
    }
}

// V merged bf16 (B,S,512) -> Vt bf16 (B,H,DH,S)
__global__ void transpose_v_kernel(const u16* __restrict__ V, u16* __restrict__ Vt) {
    int z = blockIdx.z;
    int b = z >> 3, h = z & 7;
    const u16* in = V + (long)b * S_LEN * DMODEL + h * DHEAD;
    u16* out = Vt + (long)z * DHEAD * S_LEN;
    __shared__ u16 t[32][33];
    int tx = threadIdx.x, ty = threadIdx.y;
    int r = blockIdx.y * 32 + ty;  // s
    int c = blockIdx.x * 32 + tx;  // d
    t[ty][tx] = in[(long)r * DMODEL + c];
    __syncthreads();
    int orow = blockIdx.x * 32 + ty;  // d
    int ocol = blockIdx.y * 32 + tx;  // s
    out[(long)orow * S_LEN + ocol] = t[tx][ty];
}

// ---------------- GEMM: C(4096x512) = A(4096x512) @ W + bias; block tile (TM*32) x 64,
// 4 waves (2x2), wave tile (TM*16) x 32.
template <bool F32OUT, int TM>
static __device__ __forceinline__ void gemm_body(const u16* __restrict__ A,
                                                 const u16* __restrict__ Wt,
                                                 const float* __restrict__ bias,
                                                 void* __restrict__ Cp, float oscale) {
    const int lane = threadIdx.x & 63;
    const int wave = threadIdx.x >> 6;
    const int wr = wave >> 1, wc = wave & 1;
    const int m0 = blockIdx.y * (TM * 32) + wr * (TM * 16);
    const int n0 = blockIdx.x * 64 + wc * 32;
    const int cidx = lane & 15;
    const int kg = lane >> 4;

    const u16* aptr[TM];
    const u16* bptr[2];
#pragma unroll
    for (int t = 0; t < TM; ++t)
        aptr[t] = A + (long)(m0 + t * 16 + cidx) * DMODEL + kg * 8;
#pragma unroll
    for (int t = 0; t < 2; ++t)
        bptr[t] = Wt + (long)(n0 + t * 16 + cidx) * DMODEL + kg * 8;

    const f32x4 fz = {0.f, 0.f, 0.f, 0.f};
    f32x4 acc[TM][2];
#pragma unroll
    for (int i = 0; i < TM; ++i)
#pragma unroll
        for (int j = 0; j < 2; ++j) acc[i][j] = fz;

#pragma unroll 4
    for (int k0 = 0; k0 < 512; k0 += 32) {
        bf16x8 a[TM], b[2];
#pragma unroll
        for (int t = 0; t < TM; ++t) a[t] = ld8(aptr[t] + k0);
#pragma unroll
        for (int t = 0; t < 2; ++t) b[t] = ld8(bptr[t] + k0);
#pragma unroll
        for (int i = 0; i < TM; ++i)
#pragma unroll
            for (int j = 0; j < 2; ++j)
                acc[i][j] = __builtin_amdgcn_mfma_f32_16x16x32_bf16(a[i], b[j], acc[i][j], 0, 0, 0);
    }

#pragma unroll
    for (int j = 0; j < 2; ++j) {
        int col = n0 + j * 16 + cidx;
        float bv = bias[col];
#pragma unroll
        for (int i = 0; i < TM; ++i) {
#pragma unroll
            for (int r = 0; r < 4; ++r) {
                int row = m0 + i * 16 + kg * 4 + r;
                float val = (acc[i][j][r] + bv) * oscale;
                if (F32OUT) {
                    ((float*)Cp)[(long)row * DMODEL + col] = val;
                } else {
                    ((u16*)Cp)[(long)row * DMODEL + col] = f2bf(val);
                }
            }
        }
    }
}

__global__ __launch_bounds__(256) void qkv_gemm_kernel(
    const u16* __restrict__ Aqkv,
    const u16* __restrict__ wtall,
    const float* __restrict__ bq, const float* __restrict__ bk, const float* __restrict__ bv,
    u16* __restrict__ Q, u16* __restrict__ K, u16* __restrict__ V) {
    const u16* A = Aqkv + (long)blockIdx.z * 2097152;
    const u16* W = wtall + (long)(blockIdx.z + 1) * 262144;  // [wo, wq, wk, wv]
    const float* b;
    u16* C;
    float sc = 1.f;
    if (blockIdx.z == 0) { b = bq; C = Q; sc = QSCALE; }  // fold 1/sqrt(DH)*log2e into Q
    else if (blockIdx.z == 1) { b = bk; C = K; }
    else { b = bv; C = V; }
    gemm_body<false, 4>(A, W, b, C, sc);
}

__global__ __launch_bounds__(256) void out_gemm_kernel(const u16* __restrict__ A,
                                                       const u16* __restrict__ Wt,
                                                       const float* __restrict__ bias,
                                                       float* __restrict__ C) {
    gemm_body<true, 2>(A, Wt, bias, C, 1.f);
}

// ---------------- flash attention, S^T formulation ----------------
// grid: (S/64, B*H, KSPLIT), block 256 (4 waves). Wave w owns 16 q-rows (q = q0 + lane&15).
// QK^T computed transposed: D = K_tile . Q^T, so each lane holds 16 keys of ONE q-row.
// Softmax reductions are in-lane trees + 2 shfls; P^T packs as 4 ds_write_b64.
__global__ __launch_bounds__(256) void attn_kernel(const u16* __restrict__ Q,
                                                   const u16* __restrict__ K,
                                                   const u16* __restrict__ Vt,
                                                   const float* __restrict__ mask,
                                                   const int* __restrict__ flags,
                                                   u16* __restrict__ Opart,
                                                   float* __restrict__ ML) {
    const int tid = threadIdx.x;
    const int lane = tid & 63;
    const int wave = tid >> 6;
    const int cidx = lane & 15;   // q-row (QK^T B-operand col / PV B-col); d-row for V A-frag
    const int kg = lane >> 4;
    const int bh = blockIdx.y;
    const int b = bh >> 3, h = bh & 7;
    const int q0 = blockIdx.x * 64 + wave * 16;
    const int z = blockIdx.z;
    const int k0z = z * KRANGE;

    __shared__ u16 kt_lds[64 * 64];   // [key-local][dh], XOR-swizzled 8-blocks
    __shared__ u16 vt_lds[64 * 64];   // [dh][key-local], XOR-swizzled
    __shared__ u16 p_lds[4][16 * 64]; // per-wave P^T as [q][key], XOR-swizzled
    u16* pw = p_lds[wave];

    // Q fragment: lane holds Q[q0+cidx][kg*8+j] (+32). Serves as B-operand of K.Q^T.
    const long qbase = ((long)(b * S_LEN + q0 + cidx)) * DMODEL + h * DHEAD + kg * 8;
    bf16x8 aq0 = ld8(Q + qbase);
    bf16x8 aq1 = ld8(Q + qbase + 32);

    const f32x4 fz = {0.f, 0.f, 0.f, 0.f};
    f32x4 acc[4];  // O^T accumulator: lane holds O[q0+cidx][16nt+4kg+r]
#pragma unroll
    for (int nt = 0; nt < 4; ++nt) acc[nt] = fz;
    float mrow = -1e30f;  // per-lane: one q-row (log2 domain)
    float lrow = 0.f;

    // staging roles: 512 16B slots over 256 threads
    const int krow0 = tid >> 3, kseg0 = tid & 7;  // rows 0..31
    const int krow1 = krow0 + 32;                 // rows 32..63
    const u16* kgbase = K + ((long)(b * S_LEN + k0z)) * DMODEL + h * DHEAD;
    const u16* vgbase = Vt + ((long)bh * DHEAD) * S_LEN + k0z;
    const int kd0 = krow0 * 64 + (((kseg0 ^ (krow0 & 7))) << 3);
    const int kd1 = krow1 * 64 + (((kseg0 ^ (krow1 & 7))) << 3);
    const int* flagrow = flags + b * 1024 + blockIdx.x * 32 + z * (KRANGE / 64);

    for (int it = 0; it < KRANGE / 64; ++it) {
        const int kt = it * 64;
        const int flg = flagrow[it];
        __syncthreads();  // previous iteration's LDS reads complete
        *(u16x8*)&kt_lds[kd0] = *(const u16x8*)(kgbase + (long)(kt + krow0) * DMODEL + kseg0 * 8);
        *(u16x8*)&kt_lds[kd1] = *(const u16x8*)(kgbase + (long)(kt + krow1) * DMODEL + kseg0 * 8);
        *(u16x8*)&vt_lds[kd0] = *(const u16x8*)(vgbase + (long)krow0 * S_LEN + kt + kseg0 * 8);
        *(u16x8*)&vt_lds[kd1] = *(const u16x8*)(vgbase + (long)krow1 * S_LEN + kt + kseg0 * 8);
        __syncthreads();

        // ---- S^T tile = K . Q^T : 64 keys x 16 q. Lane holds keys 16ct+4kg+r of q=q0+cidx.
        f32x4 sacc[4];
#pragma unroll
        for (int ct = 0; ct < 4; ++ct) sacc[ct] = fz;
#pragma unroll
        for (int ct = 0; ct < 4; ++ct) {
            int r = ct * 16 + cidx;
            bf16x8 kv0 = ld8(&kt_lds[r * 64 + ((kg ^ (r & 7)) << 3)]);
            bf16x8 kv1 = ld8(&kt_lds[r * 64 + (((4 ^ kg) ^ (r & 7)) << 3)]);
            sacc[ct] = __builtin_amdgcn_mfma_f32_16x16x32_bf16(kv0, aq0, sacc[ct], 0, 0, 0);
            sacc[ct] = __builtin_amdgcn_mfma_f32_16x16x32_bf16(kv1, aq1, sacc[ct], 0, 0, 0);
        }
        // mask slow path (rare): lane's q-row is fixed, keys contiguous -> f32x4 loads
        if (flg) {
            const float* mb = mask + ((long)(b * S_LEN + q0 + cidx)) * S_LEN + k0z + kt + kg * 4;
#pragma unroll
            for (int ct = 0; ct < 4; ++ct) {
                f32x4 mv = *(const f32x4*)(mb + ct * 16);
#pragma unroll
                for (int r = 0; r < 4; ++r) sacc[ct][r] -= MASKC * mv[r];
            }
        }
        // ---- online softmax (exp2 domain), per-lane over 16 keys + 2 shfls across kg ----
        float mx = fmaxf(fmaxf(fmaxf(sacc[0][0], sacc[0][1]), fmaxf(sacc[0][2], sacc[0][3])),
                         fmaxf(fmaxf(sacc[1][0], sacc[1][1]), fmaxf(sacc[1][2], sacc[1][3])));
        float mx2 = fmaxf(fmaxf(fmaxf(sacc[2][0], sacc[2][1]), fmaxf(sacc[2][2], sacc[2][3])),
                          fmaxf(fmaxf(sacc[3][0], sacc[3][1]), fmaxf(sacc[3][2], sacc[3][3])));
        mx = fmaxf(mx, mx2);
        mx = fmaxf(mx, __shfl_xor(mx, 16));
        mx = fmaxf(mx, __shfl_xor(mx, 32));
        float mnew = fmaxf(mrow, mx);
        float alpha = exp2f(mrow - mnew);
        mrow = mnew;
        float pvv[4][4];
        float s = 0.f;
#pragma unroll
        for (int ct = 0; ct < 4; ++ct)
#pragma unroll
            for (int r = 0; r < 4; ++r) {
                float pp = exp2f(sacc[ct][r] - mnew);
                pvv[ct][r] = pp;
                s += pp;
            }
        s += __shfl_xor(s, 16);
        s += __shfl_xor(s, 32);
        lrow = lrow * alpha + s;
#pragma unroll
        for (int nt = 0; nt < 4; ++nt) acc[nt] = acc[nt] * alpha;
        // ---- P^T -> per-wave LDS [q][key]: 4 packed b64 writes (keys 16ct+4kg..+3) ----
#pragma unroll
        for (int ct = 0; ct < 4; ++ct) {
            u32x2 d;
            d[0] = pk2bf(pvv[ct][0], pvv[ct][1]);
            d[1] = pk2bf(pvv[ct][2], pvv[ct][3]);
            int blk = 2 * ct + (kg >> 1);
            *(u32x2*)&pw[cidx * 64 + ((blk ^ (cidx & 7)) << 3) + (kg & 1) * 4] = d;
        }
        // B-frag of P^T: lane needs P[q=cidx][keys kg*8..+7] (and +32)
        bf16x8 pf0 = ld8(&pw[cidx * 64 + ((kg ^ (cidx & 7)) << 3)]);
        bf16x8 pf1 = ld8(&pw[cidx * 64 + (((4 ^ kg) ^ (cidx & 7)) << 3)]);
        // ---- O^T += V^T . P^T ----
#pragma unroll
        for (int nt = 0; nt < 4; ++nt) {
            int rr = nt * 16 + cidx;
            bf16x8 v0 = ld8(&vt_lds[rr * 64 + ((kg ^ (rr & 7)) << 3)]);
            bf16x8 v1 = ld8(&vt_lds[rr * 64 + (((4 ^ kg) ^ (rr & 7)) << 3)]);
            acc[nt] = __builtin_amdgcn_mfma_f32_16x16x32_bf16(v0, pf0, acc[nt], 0, 0, 0);
            acc[nt] = __builtin_amdgcn_mfma_f32_16x16x32_bf16(v1, pf1, acc[nt], 0, 0, 0);
        }
    }
    // epilogue: lane holds O[q0+cidx][16nt+4kg+r] -> packed 8B stores
    const long obase = (((long)(z * 16 + bh)) * S_LEN + q0 + cidx) * DHEAD;
#pragma unroll
    for (int nt = 0; nt < 4; ++nt) {
        u32x2 d;
        d[0] = pk2bf(acc[nt][0], acc[nt][1]);
        d[1] = pk2bf(acc[nt][2], acc[nt][3]);
        *(u32x2*)(Opart + obase + nt * 16 + kg * 4) = d;
    }
    if (lane < 16) {
        long mi = ((long)(z * 16 + bh)) * S_LEN + q0 + cidx;
        ML[mi * 2] = mrow;
        ML[mi * 2 + 1] = lrow;
    }
}

// combine KSPLIT partials -> merged bf16 (B,S,512). 8 cols/thread, 32 rows/block, grid 1024.
__global__ __launch_bounds__(256) void attn_combine_kernel(const u16* __restrict__ Opart,
                                                           const float* __restrict__ ML,
                                                           u16* __restrict__ Ab) {
    const int tid = threadIdx.x;
    const long rr = (long)blockIdx.x * 32 + (tid >> 3);  // bh*2048 + q
    const int c8 = (tid & 7) * 8;
    const int bh = (int)(rr >> 11);
    const int q = (int)(rr & 2047);
    const int b = bh >> 3, h = bh & 7;

    float m[KSPLIT], l[KSPLIT];
#pragma unroll
    for (int zz = 0; zz < KSPLIT; ++zz) {
        long mi = ((long)(zz * 16 + bh)) * S_LEN + q;
        m[zz] = ML[mi * 2];
        l[zz] = ML[mi * 2 + 1];
    }
    float M = m[0];
#pragma unroll
    for (int zz = 1; zz < KSPLIT; ++zz) M = fmaxf(M, m[zz]);
    float L = 0.f, e[KSPLIT];
#pragma unroll
    for (int zz = 0; zz < KSPLIT; ++zz) { e[zz] = exp2f(m[zz] - M); L += e[zz] * l[zz]; }
    float o[8] = {0, 0, 0, 0, 0, 0, 0, 0};
#pragma unroll
    for (int zz = 0; zz < KSPLIT; ++zz) {
        bf16x8 ov = ld8(Opart + (((long)(zz * 16 + bh)) * S_LEN + q) * DHEAD + c8);
#pragma unroll
        for (int j = 0; j < 8; ++j) o[j] += e[zz] * (float)ov[j];
    }
    float invL = 1.f / L;
    u16x8 w;
#pragma unroll
    for (int j = 0; j < 8; ++j) w[j] = f2bf(o[j] * invL);
    *(u16x8*)(Ab + ((long)(b * S_LEN + q)) * DMODEL + h * DHEAD + c8) = w;
}

extern "C" void kernel_launch(void* const* d_in, const int* in_sizes, int n_in,
                              void* d_out, int out_size, void* d_ws, size_t ws_size,
                              hipStream_t stream) {
    const float* q_in = (const float*)d_in[0];
    const float* k_in = (const float*)d_in[1];
    const float* v_in = (const float*)d_in[2];
    const float* mask = (const float*)d_in[3];
    const float* wq = (const float*)d_in[4];
    const float* bq = (const float*)d_in[5];
    const float* wk = (const float*)d_in[6];
    const float* bk = (const float*)d_in[7];
    const float* wv = (const float*)d_in[8];
    const float* bv = (const float*)d_in[9];
    const float* wo = (const float*)d_in[10];
    const float* bo = (const float*)d_in[11];

    // ws layout (u16 units). Regions ordered so attn can alias dead space:
    u16* ws = (u16*)d_ws;
    u16* Qb = ws;                       // 2.1M  projected Q (pre-scaled QSCALE)
    u16* Kb = Qb + 2097152;             // 2.1M
    u16* Vt = Kb + 2097152;             // 2.1M  V transposed (B,H,DH,S)
    u16* wtall = Vt + 2097152;          // 4 x 262144: [wo, wq, wk, wv]
    u16* Sreg = wtall + 4 * 262144;     // 3 x 2.1M: Aq,Ak,Av  (dead after qkv_gemm)
    u16* Vb = Sreg + 3 * 2097152;       // 2.1M  merged V    (dead after transpose_v)
    u16* Ab = Vb + 2097152;             // 2.1M  attention output (merged heads)
    int* mflags = (int*)(Ab + 2097152); // 2048 ints
    // aliases:
    u16* Opart = Sreg;                  // KSPLIT*16*2048*64 = 8.39M u16, spans Sreg+Vb ok
    float* ML = (float*)(wtall + 262144);  // over [wq,wk] slots (dead after qkv_gemm)

    prep_kernel<<<6144, 256, 0, stream>>>(q_in, k_in, v_in, wq, wk, wv, wo, mask,
                                          Sreg, wtall, mflags);
    qkv_gemm_kernel<<<dim3(8, 32, 3), 256, 0, stream>>>(Sreg, wtall, bq, bk, bv, Qb, Kb, Vb);
    transpose_v_kernel<<<dim3(2, 64, 16), dim3(32, 32), 0, stream>>>(Vb, Vt);
    attn_kernel<<<dim3(32, 16, KSPLIT), 256, 0, stream>>>(Qb, Kb, Vt, mask, mflags, Opart, ML);
    attn_combine_kernel<<<1024, 256, 0, stream>>>(Opart, ML, Ab);
    out_gemm_kernel<<<dim3(8, 64), 256, 0, stream>>>(Ab, wtall, bo, (float*)d_out);
}